// Round 1
// baseline (267.834 us; speedup 1.0000x reference)
//
#include <hip/hip_runtime.h>

#define N_CTX 2048
#define DHEAD 64
#define SCALE2 0.015625f   // (1/sqrt(64))^2
#define EPS_F 1e-6f

typedef __attribute__((ext_vector_type(8))) short short8;
typedef __attribute__((ext_vector_type(4))) short short4v;
typedef __attribute__((ext_vector_type(4))) float float4v;

__device__ __forceinline__ short f2bf(float f) {
    union { float f; unsigned u; } x; x.f = f;
    unsigned r = x.u + 0x7FFFu + ((x.u >> 16) & 1u);  // RNE
    return (short)(r >> 16);
}
__device__ __forceinline__ unsigned pack2(float a, float b) {
    return (unsigned)(unsigned short)f2bf(a) | ((unsigned)(unsigned short)f2bf(b) << 16);
}

// Layout notes (gfx950 mfma_f32_16x16x32_bf16, m89-verified):
//   A-frag: lane holds A[m=lane&15][k=8*(lane>>4)+j], j=0..7
//   B-frag: lane holds B[k=8*(lane>>4)+j][n=lane&15]
//   C/D   : lane holds C[row=4*(lane>>4)+r][col=lane&15], r=0..3
// We compute S^T = K*Q^T (M=kv, N=q, K=d) so that A reads K rows contiguously
// and B reads Q rows contiguously. PV uses A=P (via LDS round-trip), B=V via
// transposed Vt[d][kv] so B-frags read contiguously along kv.

__global__ __launch_bounds__(256, 4)
void powsm_attn(const float* __restrict__ qg, const float* __restrict__ kg,
                const float* __restrict__ vg, float* __restrict__ og)
{
    __shared__ short Ks[64][72];      // K tile, row-major bf16 (+8 pad)
    __shared__ short Vt[64][72];      // V tile transposed: Vt[d][kv]
    __shared__ short Ps[4][32][72];   // per-wave P stash: P[q][kv]
    __shared__ float Dn[4][32];       // per-wave denominator exchange

    const int bh   = blockIdx.y;
    const int tid  = threadIdx.x;
    const int wave = tid >> 6;
    const int lane = tid & 63;
    const int qd   = lane >> 4;   // quad 0..3
    const int c    = lane & 15;

    const size_t base = (size_t)bh * N_CTX * DHEAD;
    const float* qp = qg + base;
    const float* kp = kg + base;
    const float* vp = vg + base;
    float*       op = og + base;

    const int qw0 = blockIdx.x * 128 + wave * 32;

    // Hoist Q fragments (B-operand of S^T): Qf[qt][ks]
    short8 Qf[2][2];
    #pragma unroll
    for (int qt = 0; qt < 2; ++qt) {
        #pragma unroll
        for (int ks = 0; ks < 2; ++ks) {
            const float* src = qp + (size_t)(qw0 + qt*16 + c) * DHEAD + ks*32 + qd*8;
            float4v a = *(const float4v*)(src);
            float4v b = *(const float4v*)(src + 4);
            short8 f;
            f[0]=f2bf(a[0]); f[1]=f2bf(a[1]); f[2]=f2bf(a[2]); f[3]=f2bf(a[3]);
            f[4]=f2bf(b[0]); f[5]=f2bf(b[1]); f[6]=f2bf(b[2]); f[7]=f2bf(b[3]);
            Qf[qt][ks] = f;
        }
    }

    float4v Oacc[2][4];   // [qt][nt]
    #pragma unroll
    for (int qt = 0; qt < 2; ++qt)
        #pragma unroll
        for (int nt = 0; nt < 4; ++nt)
            Oacc[qt][nt] = (float4v){0.f, 0.f, 0.f, 0.f};
    float denom0 = 0.f, denom1 = 0.f;

    const int tr = tid >> 4;   // V-transpose 4x4 block coords
    const int tc = tid & 15;

    for (int kv0 = 0; kv0 < N_CTX; kv0 += 64) {
        __syncthreads();   // previous iter's K/V frag reads complete

        // ---- stage K -> Ks (row-major bf16), coalesced float4 ----
        #pragma unroll
        for (int u = 0; u < 4; ++u) {
            int s = tid + u * 256;
            int r = s >> 4, cg = (s & 15) << 2;
            float4v f = *(const float4v*)(kp + (size_t)(kv0 + r) * DHEAD + cg);
            short4v h; h[0]=f2bf(f[0]); h[1]=f2bf(f[1]); h[2]=f2bf(f[2]); h[3]=f2bf(f[3]);
            *(short4v*)&Ks[r][cg] = h;
        }
        // ---- stage V -> Vt transposed via 4x4 register transpose ----
        {
            float4v f0 = *(const float4v*)(vp + (size_t)(kv0 + 4*tr + 0) * DHEAD + 4*tc);
            float4v f1 = *(const float4v*)(vp + (size_t)(kv0 + 4*tr + 1) * DHEAD + 4*tc);
            float4v f2 = *(const float4v*)(vp + (size_t)(kv0 + 4*tr + 2) * DHEAD + 4*tc);
            float4v f3 = *(const float4v*)(vp + (size_t)(kv0 + 4*tr + 3) * DHEAD + 4*tc);
            #pragma unroll
            for (int kk = 0; kk < 4; ++kk) {
                short4v h; h[0]=f2bf(f0[kk]); h[1]=f2bf(f1[kk]);
                           h[2]=f2bf(f2[kk]); h[3]=f2bf(f3[kk]);
                *(short4v*)&Vt[4*tc + kk][4*tr] = h;
            }
        }
        __syncthreads();

        // ---- S^T = K * Q^T, then p = s^2*SCALE2, stash P[q][kv] ----
        #pragma unroll
        for (int mt = 0; mt < 4; ++mt) {
            float4v s0 = {0.f,0.f,0.f,0.f}, s1 = {0.f,0.f,0.f,0.f};
            #pragma unroll
            for (int ks = 0; ks < 2; ++ks) {
                short8 af = *(const short8*)&Ks[mt*16 + c][ks*32 + qd*8];
                s0 = __builtin_amdgcn_mfma_f32_16x16x32_bf16(af, Qf[0][ks], s0, 0, 0, 0);
                s1 = __builtin_amdgcn_mfma_f32_16x16x32_bf16(af, Qf[1][ks], s1, 0, 0, 0);
            }
            {
                float p0 = s0[0]*s0[0]*SCALE2, p1 = s0[1]*s0[1]*SCALE2;
                float p2 = s0[2]*s0[2]*SCALE2, p3 = s0[3]*s0[3]*SCALE2;
                denom0 += (p0 + p1) + (p2 + p3);
                *(unsigned*)&Ps[wave][c][mt*16 + qd*4]     = pack2(p0, p1);
                *(unsigned*)&Ps[wave][c][mt*16 + qd*4 + 2] = pack2(p2, p3);
            }
            {
                float p0 = s1[0]*s1[0]*SCALE2, p1 = s1[1]*s1[1]*SCALE2;
                float p2 = s1[2]*s1[2]*SCALE2, p3 = s1[3]*s1[3]*SCALE2;
                denom1 += (p0 + p1) + (p2 + p3);
                *(unsigned*)&Ps[wave][16 + c][mt*16 + qd*4]     = pack2(p0, p1);
                *(unsigned*)&Ps[wave][16 + c][mt*16 + qd*4 + 2] = pack2(p2, p3);
            }
        }

        // ---- O += P * V ----
        #pragma unroll
        for (int pk = 0; pk < 2; ++pk) {
            short8 Pf0 = *(const short8*)&Ps[wave][c][pk*32 + qd*8];
            short8 Pf1 = *(const short8*)&Ps[wave][16 + c][pk*32 + qd*8];
            #pragma unroll
            for (int nt = 0; nt < 4; ++nt) {
                short8 bf = *(const short8*)&Vt[nt*16 + c][pk*32 + qd*8];
                Oacc[0][nt] = __builtin_amdgcn_mfma_f32_16x16x32_bf16(Pf0, bf, Oacc[0][nt], 0, 0, 0);
                Oacc[1][nt] = __builtin_amdgcn_mfma_f32_16x16x32_bf16(Pf1, bf, Oacc[1][nt], 0, 0, 0);
            }
        }
    }

    // ---- denominator: reduce partials across the 4 quads ----
    {
        float d0 = denom0;
        d0 += __shfl_xor(d0, 16);
        d0 += __shfl_xor(d0, 32);
        float d1 = denom1;
        d1 += __shfl_xor(d1, 16);
        d1 += __shfl_xor(d1, 32);
        if (qd == 0) { Dn[wave][c] = d0; Dn[wave][16 + c] = d1; }
    }
    __syncthreads();

    // ---- epilogue: scale by 1/(denom+eps), store ----
    #pragma unroll
    for (int qt = 0; qt < 2; ++qt) {
        #pragma unroll
        for (int r = 0; r < 4; ++r) {
            float inv = 1.0f / (Dn[wave][qt*16 + qd*4 + r] + EPS_F);
            float* dst = op + (size_t)(qw0 + qt*16 + qd*4 + r) * DHEAD + c;
            #pragma unroll
            for (int nt = 0; nt < 4; ++nt)
                dst[nt*16] = Oacc[qt][nt][r] * inv;
        }
    }
}

extern "C" void kernel_launch(void* const* d_in, const int* in_sizes, int n_in,
                              void* d_out, int out_size, void* d_ws, size_t ws_size,
                              hipStream_t stream) {
    const float* q = (const float*)d_in[0];
    const float* k = (const float*)d_in[1];
    const float* v = (const float*)d_in[2];
    float* out = (float*)d_out;
    dim3 grid(N_CTX / 128, 64, 1);   // (q-tiles, B*H)
    powsm_attn<<<grid, dim3(256, 1, 1), 0, stream>>>(q, k, v, out);
}

// Round 3
// 209.235 us; speedup vs baseline: 1.2801x; 1.2801x over previous
//
#include <hip/hip_runtime.h>

#define N_CTX 2048
#define DHEAD 64
#define SCALE_F 0.125f
#define EPS_F 1e-6f
#define KT 64
#define NITER (N_CTX / KT)
#define QBLK 256           // q per block: 4 waves x 64

typedef __attribute__((ext_vector_type(8))) short short8;
typedef __attribute__((ext_vector_type(4))) short short4v;
typedef __attribute__((ext_vector_type(4))) float float4v;
typedef __attribute__((ext_vector_type(2))) unsigned uint2v;
typedef __attribute__((ext_vector_type(4))) unsigned uint4v;

// ---- bf16 pack: HW cvt_pk on device, parse-only fallback for host pass ----
#if defined(__HIP_DEVICE_COMPILE__) && __has_builtin(__builtin_amdgcn_cvt_pk_bf16_f32)
typedef __attribute__((ext_vector_type(2))) __bf16 bf16x2;
__device__ __forceinline__ unsigned pack2(float a, float b) {
    union { bf16x2 v; unsigned u; } x;
    x.v = __builtin_amdgcn_cvt_pk_bf16_f32(a, b);
    return x.u;
}
#else
__device__ __forceinline__ unsigned bf1(float f) {
    union { float f; unsigned u; } x; x.f = f;
    return (x.u + 0x7FFFu + ((x.u >> 16) & 1u)) >> 16;
}
__device__ __forceinline__ unsigned pack2(float a, float b) {
    return bf1(a) | (bf1(b) << 16);
}
#endif

// ---- K=16 bf16 MFMA (A,B = 4 bf16/lane = short4v; C/D = float4) ----
// __has_builtin is only meaningful in the device pass (host pass checks the
// x86 target and returns false even for aux-target-callable builtins).
#if defined(__HIP_DEVICE_COMPILE__)
  #if __has_builtin(__builtin_amdgcn_mfma_f32_16x16x16bf16_1k)
    #define MFMA16(a, b, c) __builtin_amdgcn_mfma_f32_16x16x16bf16_1k(a, b, c, 0, 0, 0)
  #elif __has_builtin(__builtin_amdgcn_mfma_f32_16x16x16_bf16_1k)
    #define MFMA16(a, b, c) __builtin_amdgcn_mfma_f32_16x16x16_bf16_1k(a, b, c, 0, 0, 0)
  #else
    __device__ __forceinline__ float4v mfma16_asm(short4v a, short4v b, float4v c) {
        asm volatile("v_mfma_f32_16x16x16_bf16 %0, %1, %2, %0"
                     : "+v"(c) : "v"(a), "v"(b));
        return c;
    }
    #define MFMA16(a, b, c) mfma16_asm(a, b, c)
  #endif
#else
  #define MFMA16(a, b, c) (c)   /* host pass: parse-only, never executed */
#endif

// Layouts (gfx950, m89-verified):
//  mfma 16x16x32: A[m=lane&15][k=8q+j], B[k=8q+j][n=lane&15], C[row=4q+r][col=lane&15]
//  mfma 16x16x16: A[m=lane&15][k=4q+j], B[k=4q+j][n=lane&15]  (q = lane>>4)
// S^T = K*Q^T (M=kv,N=q,K=d). Its C-layout rows kv=4q+r match the K=16 A-frag
// k=4q+j EXACTLY -> square in registers, pack, feed PV with zero transform.

__global__ __launch_bounds__(256, 2)
void powsm_attn(const float* __restrict__ qg, const float* __restrict__ kg,
                const float* __restrict__ vg, float* __restrict__ og)
{
    __shared__ short Ks[64][72];   // K tile row-major bf16 (pad 72)
    __shared__ short Vt[64][68];   // V transposed Vt[d][kv] (pad 68: conflict-free b64 ops)
    __shared__ float Dn[4][64];    // per-wave denominator exchange

    const int bh   = blockIdx.y;
    const int tid  = threadIdx.x;
    const int wave = tid >> 6;
    const int lane = tid & 63;
    const int qd   = lane >> 4;    // quad 0..3
    const int c    = lane & 15;

    const size_t base = (size_t)bh * N_CTX * DHEAD;
    const float* qp = qg + base;
    const float* kp = kg + base;
    const float* vp = vg + base;
    float*       op = og + base;

    const int qw0 = blockIdx.x * QBLK + wave * 64;

    // ---- hoist Q B-frags (16x16x32), SCALE folded in ----
    short8 Qf[4][2];
    #pragma unroll
    for (int qt = 0; qt < 4; ++qt) {
        #pragma unroll
        for (int ks = 0; ks < 2; ++ks) {
            const float* src = qp + (size_t)(qw0 + qt*16 + c) * DHEAD + ks*32 + qd*8;
            float4v a = *(const float4v*)(src);
            float4v b = *(const float4v*)(src + 4);
            uint4v u;
            u[0] = pack2(a[0]*SCALE_F, a[1]*SCALE_F);
            u[1] = pack2(a[2]*SCALE_F, a[3]*SCALE_F);
            u[2] = pack2(b[0]*SCALE_F, b[1]*SCALE_F);
            u[3] = pack2(b[2]*SCALE_F, b[3]*SCALE_F);
            union { uint4v u; short8 s; } cv; cv.u = u;
            Qf[qt][ks] = cv.s;
        }
    }

    float4v Oacc[4][4];            // [qt][nt]
    #pragma unroll
    for (int qt = 0; qt < 4; ++qt)
        #pragma unroll
        for (int nt = 0; nt < 4; ++nt)
            Oacc[qt][nt] = (float4v){0.f, 0.f, 0.f, 0.f};
    float4v dacc[4];
    #pragma unroll
    for (int qt = 0; qt < 4; ++qt) dacc[qt] = (float4v){0.f, 0.f, 0.f, 0.f};

    const int kr = tid >> 4;       // K-stage row (+u*16), V 4-row group
    const int kc = tid & 15;       // col group

    // ---- prefetch tile 0 ----
    float4v pK[4], pV[4];
    #pragma unroll
    for (int u = 0; u < 4; ++u)
        pK[u] = *(const float4v*)(kp + (size_t)(kr + u*16) * DHEAD + kc*4);
    #pragma unroll
    for (int j = 0; j < 4; ++j)
        pV[j] = *(const float4v*)(vp + (size_t)(4*kr + j) * DHEAD + kc*4);

    #pragma unroll 1
    for (int kvi = 0; kvi < NITER; ++kvi) {
        __syncthreads();   // previous iter's frag reads complete

        // ---- stage K (row-major) ----
        #pragma unroll
        for (int u = 0; u < 4; ++u) {
            uint2v w; w[0] = pack2(pK[u][0], pK[u][1]); w[1] = pack2(pK[u][2], pK[u][3]);
            *(uint2v*)&Ks[kr + u*16][kc*4] = w;
        }
        // ---- stage V transposed: Vt[d][kv] ----
        #pragma unroll
        for (int kk = 0; kk < 4; ++kk) {
            uint2v w; w[0] = pack2(pV[0][kk], pV[1][kk]); w[1] = pack2(pV[2][kk], pV[3][kk]);
            *(uint2v*)&Vt[4*kc + kk][4*kr] = w;
        }
        __syncthreads();

        // ---- prefetch next tile (overlaps compute) ----
        if (kvi + 1 < NITER) {
            const float* kn = kp + (size_t)(kvi + 1) * KT * DHEAD;
            const float* vn = vp + (size_t)(kvi + 1) * KT * DHEAD;
            #pragma unroll
            for (int u = 0; u < 4; ++u)
                pK[u] = *(const float4v*)(kn + (size_t)(kr + u*16) * DHEAD + kc*4);
            #pragma unroll
            for (int j = 0; j < 4; ++j)
                pV[j] = *(const float4v*)(vn + (size_t)(4*kr + j) * DHEAD + kc*4);
        }

        // ---- per 16-kv chunk: S^T -> square -> PV (fused, no P round-trip) ----
        #pragma unroll
        for (int mt = 0; mt < 4; ++mt) {
            float4v s[4];
            #pragma unroll
            for (int qt = 0; qt < 4; ++qt) s[qt] = (float4v){0.f, 0.f, 0.f, 0.f};
            #pragma unroll
            for (int ks = 0; ks < 2; ++ks) {
                short8 af = *(const short8*)&Ks[mt*16 + c][ks*32 + qd*8];
                #pragma unroll
                for (int qt = 0; qt < 4; ++qt)
                    s[qt] = __builtin_amdgcn_mfma_f32_16x16x32_bf16(af, Qf[qt][ks], s[qt], 0, 0, 0);
            }
            short4v pa[4];
            #pragma unroll
            for (int qt = 0; qt < 4; ++qt) {
                float p0 = s[qt][0]*s[qt][0], p1 = s[qt][1]*s[qt][1];
                float p2 = s[qt][2]*s[qt][2], p3 = s[qt][3]*s[qt][3];
                dacc[qt][0] += p0; dacc[qt][1] += p1;
                dacc[qt][2] += p2; dacc[qt][3] += p3;
                union { uint2v u; short4v s; } cv;
                cv.u[0] = pack2(p0, p1); cv.u[1] = pack2(p2, p3);
                pa[qt] = cv.s;
            }
            #pragma unroll
            for (int nt = 0; nt < 4; ++nt) {
                short4v bf = *(const short4v*)&Vt[nt*16 + c][mt*16 + qd*4];
                #pragma unroll
                for (int qt = 0; qt < 4; ++qt)
                    Oacc[qt][nt] = MFMA16(pa[qt], bf, Oacc[qt][nt]);
            }
        }
    }

    // ---- denominator: full sum per q via cross-quad reduce ----
    #pragma unroll
    for (int qt = 0; qt < 4; ++qt) {
        float d = (dacc[qt][0] + dacc[qt][1]) + (dacc[qt][2] + dacc[qt][3]);
        d += __shfl_xor(d, 16);
        d += __shfl_xor(d, 32);
        if (qd == 0) Dn[wave][qt*16 + c] = d;
    }
    __syncthreads();

    // ---- epilogue ----
    #pragma unroll
    for (int qt = 0; qt < 4; ++qt) {
        #pragma unroll
        for (int r = 0; r < 4; ++r) {
            float inv = 1.0f / (Dn[wave][qt*16 + qd*4 + r] + EPS_F);
            float* dst = op + (size_t)(qw0 + qt*16 + qd*4 + r) * DHEAD + c;
            #pragma unroll
            for (int nt = 0; nt < 4; ++nt)
                dst[nt*16] = Oacc[qt][nt][r] * inv;
        }
    }
}

extern "C" void kernel_launch(void* const* d_in, const int* in_sizes, int n_in,
                              void* d_out, int out_size, void* d_ws, size_t ws_size,
                              hipStream_t stream) {
    const float* q = (const float*)d_in[0];
    const float* k = (const float*)d_in[1];
    const float* v = (const float*)d_in[2];
    float* out = (float*)d_out;
    dim3 grid(N_CTX / QBLK, 64, 1);   // (8 q-tiles, B*H) = 512 blocks = 2/CU
    powsm_attn<<<grid, dim3(256, 1, 1), 0, stream>>>(q, k, v, out);
}